// Round 5
// baseline (225.820 us; speedup 1.0000x reference)
//
#include <hip/hip_runtime.h>
#include <hip/hip_fp16.h>
#include <math.h>

// Problem constants (fixed by the reference setup_inputs)
constexpr int NH = 8;     // heads
constexpr int D = 32;     // head dim (c/nh)
constexpr int C = 256;    // channels
constexpr int H0 = 128;
constexpr int W0 = 128;
constexpr int PIX = H0 * W0;   // 16384
constexpr int LBLK = 4096;     // (H0/2)*(W0/2)
constexpr int K4 = 32;         // 4*k candidates
constexpr int KSTH = 260;      // V LDS row stride in halves (520 B -> <=2-way banks)
constexpr int KST = 258;       // fp32 fallback stride

typedef _Float16 half2_t __attribute__((ext_vector_type(2)));

#if defined(__has_builtin)
#if __has_builtin(__builtin_amdgcn_fdot2)
#define HAVE_FDOT2 1
#endif
#endif

__device__ __forceinline__ float fdot2_acc(half2_t a, half2_t b, float c) {
#ifdef HAVE_FDOT2
  return __builtin_amdgcn_fdot2(a, b, c, false);
#else
  return c + (float)a.x * (float)b.x + (float)a.y * (float)b.y;
#endif
}

// ---------------------------------------------------------------------------
// Pass 1: transpose k/v only, [b, C, PIX] -> fp16 [b, PIX, C].
// grid = (PIX/64, C/64, 4)  z: 0,1 = k(b=0,1); 2,3 = v(b=0,1)
// ---------------------------------------------------------------------------
__global__ __launch_bounds__(256) void transpose_kv_kernel(
    const float* __restrict__ k, const float* __restrict__ v,
    __half* __restrict__ kT, __half* __restrict__ vT)
{
  __shared__ float tile[64 * 65];
  const int z = blockIdx.z;
  const int b = z & 1;
  const int arr = z >> 1;   // 0=k, 1=v
  const float* src = (arr == 0 ? k : v) + (size_t)b * C * PIX;
  __half* dst = (arr == 0 ? kT : vT) + (size_t)b * PIX * C;

  const int p0 = blockIdx.x * 64;
  const int c0 = blockIdx.y * 64;
  const int t15 = threadIdx.x & 15;
  const int thi4 = threadIdx.x >> 4;   // 0..15

#pragma unroll
  for (int r = 0; r < 4; ++r) {
    const int ch = thi4 + r * 16;      // channel row
    const int p4 = t15 * 4;            // pixel start
    float4 f = *(const float4*)&src[(size_t)(c0 + ch) * PIX + p0 + p4];
    tile[(p4 + 0) * 65 + ch] = f.x;
    tile[(p4 + 1) * 65 + ch] = f.y;
    tile[(p4 + 2) * 65 + ch] = f.z;
    tile[(p4 + 3) * 65 + ch] = f.w;
  }
  __syncthreads();

  const int t7 = threadIdx.x & 7;
  const int th8 = threadIdx.x >> 3;  // 0..31
#pragma unroll
  for (int r = 0; r < 2; ++r) {
    const int p = th8 + r * 32;
    const int c8 = t7 * 8;
    const float* tr = &tile[p * 65 + c8];
    __half2 h0 = __floats2half2_rn(tr[0], tr[1]);
    __half2 h1 = __floats2half2_rn(tr[2], tr[3]);
    __half2 h2 = __floats2half2_rn(tr[4], tr[5]);
    __half2 h3 = __floats2half2_rn(tr[6], tr[7]);
    uint4 u;
    u.x = *(unsigned*)&h0; u.y = *(unsigned*)&h1;
    u.z = *(unsigned*)&h2; u.w = *(unsigned*)&h3;
    *(uint4*)&dst[(size_t)(p0 + p) * C + c0 + c8] = u;   // 16B aligned
  }
}

// ---------------------------------------------------------------------------
// Pass 2: attention. One block per (b, l).
//  - q read from ORIGINAL [b,C,H,W] layout (L2-absorbed), stored fp16 in LDS.
//  - K gathered straight into registers (each thread is sole consumer).
//  - V gathered into LDS during staging.
//  - A exchanged via __shfl (no LDS, no extra barrier).
//  LDS: V 16,640 B + qh 2,048 B = 18,688 B -> 8 blocks/CU. ONE barrier.
// ---------------------------------------------------------------------------
__global__ __launch_bounds__(256) void cascade_attn_f16(
    const float* __restrict__ query,   // [2, C, PIX] fp32 (original layout)
    const __half* __restrict__ kT,     // [2, PIX, C] fp16
    const __half* __restrict__ vT,
    const int* __restrict__ topk,      // [2,4096,8,2] int32
    const float* __restrict__ relp,    // [2,8,128,128,32] fp32
    float* __restrict__ out_msg,       // [2,16384,256]
    float* __restrict__ out_idx)       // [2,16384,32] (float values)
{
  __shared__ __half vsh[K4 * KSTH];   // gathered V (16,640 B)
  __shared__ __half qh[4 * C];        // q fp16, [t][c] (2,048 B)

  const int tid = threadIdx.x;
  const int bid = blockIdx.x;
  const int b = bid >> 12;
  const int l = bid & (LBLK - 1);
  const int by = l >> 6, bx = l & 63;
  const int r0 = by * 2, c0 = bx * 2;

  const int* tp = topk + ((size_t)b * LBLK + l) * 16;

  const int h = tid >> 5;   // head
  const int m = tid & 31;   // candidate (QK) / head-dim lane j (PV)

  // ---- stage q from original layout: thread = channel, 2x float2 ----
  {
    const float* qp = query + (size_t)b * C * PIX + (size_t)tid * PIX + r0 * W0 + c0;
    float2 qa = *(const float2*)qp;         // row r0: t=0,1
    float2 qb = *(const float2*)(qp + W0);  // row r0+1: t=2,3
    qh[0 * C + tid] = __float2half(qa.x);
    qh[1 * C + tid] = __float2half(qa.y);
    qh[2 * C + tid] = __float2half(qb.x);
    qh[3 * C + tid] = __float2half(qb.y);
  }

  // ---- candidate pixel for this thread's V gather slice ----
  const int p = tid >> 3;        // candidate 0..31
  const int ln8 = tid & 7;
  {
    const int jj = p >> 2, o = p & 3;
    const int gp = (tp[jj * 2] * 2 + (o >> 1)) * W0 + tp[jj * 2 + 1] * 2 + (o & 1);
    const __half* src = &vT[((size_t)b * PIX + gp) * C + ln8 * 8];
#pragma unroll
    for (int i = 0; i < 4; ++i) {
      uint4 f = *(const uint4*)(src + i * 64);      // 16B aligned
      __half* dst = &vsh[p * KSTH + ln8 * 8 + i * 64];
      *(uint2*)dst = make_uint2(f.x, f.y);          // 8B aligned (row = 520 B)
      *(uint2*)(dst + 4) = make_uint2(f.z, f.w);
    }
  }

  // ---- K fragment straight to registers: K[gpix(m)][h*32 .. +31] ----
  uint4 kr[4];
  {
    const int jj = m >> 2, o = m & 3;
    const int gp = (tp[jj * 2] * 2 + (o >> 1)) * W0 + tp[jj * 2 + 1] * 2 + (o & 1);
    const __half* src = &kT[((size_t)b * PIX + gp) * C + h * D];
#pragma unroll
    for (int i = 0; i < 4; ++i) kr[i] = *(const uint4*)(src + i * 8);
  }

  // ---- prefetch rel_pos for this (h,m): 4 floats, coalesced over m ----
  const size_t rb = ((((size_t)b * NH + h) * H0 + r0) * W0 + c0) * K4 + m;
  float rl0 = relp[rb];
  float rl1 = relp[rb + K4];
  float rl2 = relp[rb + (size_t)W0 * K4];
  float rl3 = relp[rb + (size_t)W0 * K4 + K4];

  // ---- up_idx output: 4 pixels x 32 m per block ----
  if (tid < 128) {
    const int mm = tid & 31, t = tid >> 5;
    const int j2 = mm >> 2, o2 = mm & 3;
    const int pix = (tp[j2 * 2] * 2 + (o2 >> 1)) * W0 + tp[j2 * 2 + 1] * 2 + (o2 & 1);
    const int prow = r0 + (t >> 1), pcol = c0 + (t & 1);
    out_idx[((size_t)b * PIX + prow * W0 + pcol) * K4 + mm] = (float)pix;
  }
  __syncthreads();   // the ONLY barrier: q + V visible

  // ---- QK via fdot2: s[t] = q[t,h,:] . K[m,h,:] ----
  const half2_t* kh = (const half2_t*)kr;            // 16 half2
  float acc[4] = {0.f, 0.f, 0.f, 0.f};
#pragma unroll
  for (int t = 0; t < 4; ++t) {
    const half2_t* qrow = (const half2_t*)&qh[t * C + h * D];  // broadcast reads
#pragma unroll
    for (int i = 0; i < 16; ++i) acc[t] = fdot2_acc(qrow[i], kh[i], acc[t]);
  }

  const float scale = 0.17677669529663687f;  // 1/sqrt(32)
  float sv[4];
  sv[0] = acc[0] * scale + rl0;
  sv[1] = acc[1] * scale + rl1;
  sv[2] = acc[2] * scale + rl2;
  sv[3] = acc[3] * scale + rl3;

  // ---- softmax over m (32-lane xor shuffles stay inside the m group) ----
  float pr4[4];
#pragma unroll
  for (int t = 0; t < 4; ++t) {
    float x = sv[t];
    float mx = x;
#pragma unroll
    for (int off = 16; off > 0; off >>= 1) mx = fmaxf(mx, __shfl_xor(mx, off));
    float pbit = __expf(x - mx);
    float sm = pbit;
#pragma unroll
    for (int off = 16; off > 0; off >>= 1) sm += __shfl_xor(sm, off);
    pr4[t] = pbit / sm;
  }

  // ---- PV: out[t,h,j] = sum_m A[t,h,m] * V[m,h,j]; A via shfl broadcast ----
  const int lanebase = tid & 32;   // this lane's h-group base within the wave
  float o0 = 0.f, o1 = 0.f, o2 = 0.f, o3 = 0.f;
#pragma unroll
  for (int mm = 0; mm < 32; ++mm) {
    float vv = __half2float(vsh[mm * KSTH + h * D + m]);  // <=2-way banks
    const int src = lanebase + mm;
    o0 += __shfl(pr4[0], src) * vv;
    o1 += __shfl(pr4[1], src) * vv;
    o2 += __shfl(pr4[2], src) * vv;
    o3 += __shfl(pr4[3], src) * vv;
  }
  const size_t ob = ((size_t)b * PIX + (size_t)r0 * W0 + c0) * C + h * D + m;
  out_msg[ob] = o0;
  out_msg[ob + C] = o1;
  out_msg[ob + (size_t)W0 * C] = o2;
  out_msg[ob + (size_t)W0 * C + C] = o3;
}

// ---------------------------------------------------------------------------
// Fallback (Round-1 kernel, known correct): used only if ws too small.
// ---------------------------------------------------------------------------
__global__ __launch_bounds__(256) void cascade_attn_fallback(
    const float* __restrict__ query, const float* __restrict__ key,
    const float* __restrict__ value, const int* __restrict__ topk,
    const float* __restrict__ relp, float* __restrict__ out_msg,
    float* __restrict__ out_idx)
{
  __shared__ float kv[K4 * KST];
  __shared__ float qs[4 * C];
  __shared__ float as_[NH * K4 * 4];

  const int tid = threadIdx.x;
  const int bid = blockIdx.x;
  const int b = bid >> 12;
  const int l = bid & (LBLK - 1);
  const int by = l >> 6, bx = l & 63;
  const int r0 = by * 2, c0 = bx * 2;

  const size_t plane = (size_t)PIX;
  const float* qb = query + (size_t)b * C * plane;
  const float* kb = key + (size_t)b * C * plane;
  const float* vb = value + (size_t)b * C * plane;
  const int* tp = topk + ((size_t)b * LBLK + l) * 16;

  {
    const float* qp = qb + (size_t)tid * plane + r0 * W0 + c0;
    float2 a = *(const float2*)qp;
    float2 bb = *(const float2*)(qp + W0);
    qs[0 * C + tid] = a.x; qs[1 * C + tid] = a.y;
    qs[2 * C + tid] = bb.x; qs[3 * C + tid] = bb.y;
  }
#pragma unroll
  for (int it = 0; it < 16; ++it) {
    const int jj = it >> 1, x = it & 1;
    const int pr = tp[jj * 2] * 2 + x;
    const int pc = tp[jj * 2 + 1] * 2;
    float2 f = *(const float2*)(kb + (size_t)tid * plane + pr * W0 + pc);
    const int m0 = jj * 4 + x * 2;
    kv[m0 * KST + tid] = f.x;
    kv[(m0 + 1) * KST + tid] = f.y;
  }
  if (tid < 128) {
    const int m = tid & 31, t = tid >> 5;
    const int jj = m >> 2, o = m & 3;
    const int pix = (tp[jj * 2] * 2 + (o >> 1)) * W0 + tp[jj * 2 + 1] * 2 + (o & 1);
    const int prow = r0 + (t >> 1), pcol = c0 + (t & 1);
    out_idx[((size_t)b * plane + prow * W0 + pcol) * K4 + m] = (float)pix;
  }
  __syncthreads();

  const int h = tid >> 5;
  const int m = tid & 31;
  float a0 = 0.f, a1 = 0.f, a2 = 0.f, a3 = 0.f;
#pragma unroll
  for (int dq = 0; dq < 8; ++dq) {
    const int off = h * D + dq * 4;
    float4 q0 = *(const float4*)&qs[0 * C + off];
    float4 q1 = *(const float4*)&qs[1 * C + off];
    float4 q2 = *(const float4*)&qs[2 * C + off];
    float4 q3 = *(const float4*)&qs[3 * C + off];
    float2 ka = *(const float2*)&kv[m * KST + off];
    float2 kc = *(const float2*)&kv[m * KST + off + 2];
    a0 += q0.x * ka.x + q0.y * ka.y + q0.z * kc.x + q0.w * kc.y;
    a1 += q1.x * ka.x + q1.y * ka.y + q1.z * kc.x + q1.w * kc.y;
    a2 += q2.x * ka.x + q2.y * ka.y + q2.z * kc.x + q2.w * kc.y;
    a3 += q3.x * ka.x + q3.y * ka.y + q3.z * kc.x + q3.w * kc.y;
  }
  const float scale = 0.17677669529663687f;
  const size_t rb = ((((size_t)b * NH + h) * H0 + r0) * W0 + c0) * K4 + m;
  float sv[4];
  sv[0] = a0 * scale + relp[rb];
  sv[1] = a1 * scale + relp[rb + K4];
  sv[2] = a2 * scale + relp[rb + (size_t)W0 * K4];
  sv[3] = a3 * scale + relp[rb + (size_t)W0 * K4 + K4];
  float pr4[4];
#pragma unroll
  for (int t = 0; t < 4; ++t) {
    float x = sv[t];
    float mx = x;
#pragma unroll
    for (int off = 16; off > 0; off >>= 1) mx = fmaxf(mx, __shfl_xor(mx, off));
    float pbit = __expf(x - mx);
    float sm = pbit;
#pragma unroll
    for (int off = 16; off > 0; off >>= 1) sm += __shfl_xor(sm, off);
    pr4[t] = pbit / sm;
  }
  *(float4*)&as_[tid * 4] = make_float4(pr4[0], pr4[1], pr4[2], pr4[3]);
  __syncthreads();
#pragma unroll
  for (int it = 0; it < 16; ++it) {
    const int jj = it >> 1, x = it & 1;
    const int pr = tp[jj * 2] * 2 + x;
    const int pc = tp[jj * 2 + 1] * 2;
    float2 f = *(const float2*)(vb + (size_t)tid * plane + pr * W0 + pc);
    const int m0 = jj * 4 + x * 2;
    kv[m0 * KST + tid] = f.x;
    kv[(m0 + 1) * KST + tid] = f.y;
  }
  __syncthreads();
  float o0 = 0.f, o1 = 0.f, o2 = 0.f, o3 = 0.f;
#pragma unroll
  for (int mm = 0; mm < 32; ++mm) {
    float4 a4 = *(const float4*)&as_[(h * K4 + mm) * 4];
    float vv = kv[mm * KST + h * D + m];
    o0 += a4.x * vv; o1 += a4.y * vv; o2 += a4.z * vv; o3 += a4.w * vv;
  }
  const size_t ob = ((size_t)b * plane + (size_t)r0 * W0 + c0) * C + h * D + m;
  out_msg[ob] = o0;
  out_msg[ob + C] = o1;
  out_msg[ob + (size_t)W0 * C] = o2;
  out_msg[ob + (size_t)W0 * C + C] = o3;
}

extern "C" void kernel_launch(void* const* d_in, const int* in_sizes, int n_in,
                              void* d_out, int out_size, void* d_ws, size_t ws_size,
                              hipStream_t stream) {
  const float* q = (const float*)d_in[0];
  const float* k = (const float*)d_in[1];
  const float* v = (const float*)d_in[2];
  const int* tp = (const int*)d_in[3];
  const float* rp = (const float*)d_in[4];

  float* out_msg = (float*)d_out;
  float* out_idx = out_msg + (size_t)2 * PIX * C;

  const size_t n_elem = (size_t)2 * PIX * C;
  const size_t needed = 2 * n_elem * sizeof(__half);  // 33.6 MB (k/v fp16 only)
  if (ws_size >= needed) {
    __half* kT = (__half*)d_ws;
    __half* vT = kT + n_elem;
    dim3 tg(PIX / 64, C / 64, 4);
    hipLaunchKernelGGL(transpose_kv_kernel, tg, dim3(256), 0, stream, k, v, kT, vT);
    hipLaunchKernelGGL(cascade_attn_f16, dim3(2 * LBLK), dim3(256), 0, stream,
                       q, kT, vT, tp, rp, out_msg, out_idx);
  } else {
    hipLaunchKernelGGL(cascade_attn_fallback, dim3(2 * LBLK), dim3(256), 0, stream,
                       q, k, v, tp, rp, out_msg, out_idx);
  }
}

// Round 6
// 202.915 us; speedup vs baseline: 1.1129x; 1.1129x over previous
//
#include <hip/hip_runtime.h>
#include <hip/hip_fp16.h>
#include <math.h>

// Problem constants (fixed by the reference setup_inputs)
constexpr int NH = 8;     // heads
constexpr int D = 32;     // head dim (c/nh)
constexpr int C = 256;    // channels
constexpr int H0 = 128;
constexpr int W0 = 128;
constexpr int PIX = H0 * W0;   // 16384
constexpr int LBLK = 4096;     // (H0/2)*(W0/2)
constexpr int K4 = 32;         // 4*k candidates
constexpr int KSTH = 260;      // K/V LDS row stride in halves (520 B -> <=2-way banks)
constexpr int KST = 258;       // fp32 fallback stride

typedef _Float16 half2_t __attribute__((ext_vector_type(2)));

#if defined(__has_builtin)
#if __has_builtin(__builtin_amdgcn_fdot2)
#define HAVE_FDOT2 1
#endif
#endif

__device__ __forceinline__ float fdot2_acc(half2_t a, half2_t b, float c) {
#ifdef HAVE_FDOT2
  return __builtin_amdgcn_fdot2(a, b, c, false);
#else
  return c + (float)a.x * (float)b.x + (float)a.y * (float)b.y;
#endif
}

// ---------------------------------------------------------------------------
// Pass 1: transpose q/k/v [b, C, PIX] -> fp16 [b, PIX, C] in workspace.
// grid = (PIX/64, C/64, 6)  z: 0,1=q(b) 2,3=k(b) 4,5=v(b)
// ---------------------------------------------------------------------------
__global__ __launch_bounds__(256) void transpose_qkv_kernel(
    const float* __restrict__ q, const float* __restrict__ k,
    const float* __restrict__ v, __half* __restrict__ qT,
    __half* __restrict__ kT, __half* __restrict__ vT)
{
  __shared__ float tile[64 * 65];
  const int z = blockIdx.z;
  const int b = z & 1;
  const int arr = z >> 1;   // 0=q, 1=k, 2=v
  const float* src = (arr == 0 ? q : arr == 1 ? k : v) + (size_t)b * C * PIX;
  __half* dst = (arr == 0 ? qT : arr == 1 ? kT : vT) + (size_t)b * PIX * C;

  const int p0 = blockIdx.x * 64;
  const int c0 = blockIdx.y * 64;
  const int t15 = threadIdx.x & 15;
  const int thi4 = threadIdx.x >> 4;   // 0..15

#pragma unroll
  for (int r = 0; r < 4; ++r) {
    const int ch = thi4 + r * 16;      // channel row
    const int p4 = t15 * 4;            // pixel start
    float4 f = *(const float4*)&src[(size_t)(c0 + ch) * PIX + p0 + p4];
    tile[(p4 + 0) * 65 + ch] = f.x;
    tile[(p4 + 1) * 65 + ch] = f.y;
    tile[(p4 + 2) * 65 + ch] = f.z;
    tile[(p4 + 3) * 65 + ch] = f.w;
  }
  __syncthreads();

  const int t7 = threadIdx.x & 7;
  const int th8 = threadIdx.x >> 3;  // 0..31
#pragma unroll
  for (int r = 0; r < 2; ++r) {
    const int p = th8 + r * 32;
    const int c8 = t7 * 8;
    const float* tr = &tile[p * 65 + c8];
    __half2 h0 = __floats2half2_rn(tr[0], tr[1]);
    __half2 h1 = __floats2half2_rn(tr[2], tr[3]);
    __half2 h2 = __floats2half2_rn(tr[4], tr[5]);
    __half2 h3 = __floats2half2_rn(tr[6], tr[7]);
    uint4 u;
    u.x = *(unsigned*)&h0; u.y = *(unsigned*)&h1;
    u.z = *(unsigned*)&h2; u.w = *(unsigned*)&h3;
    *(uint4*)&dst[(size_t)(p0 + p) * C + c0 + c8] = u;   // 16B aligned
  }
}

// ---------------------------------------------------------------------------
// Pass 2: attention. One block per (b, l). All of q/K/V fp16 from ws.
// R4 cooperative-staging structure (proven): K+q staged to LDS, V prefetched
// to regs; QK via v_dot2_f32_f16; probs fp16 overlaid on the q buffer.
// LDS: kvh 16,640 B + qph 2,048 B = 18,688 B -> 8 blocks/CU (32 waves/CU).
// ---------------------------------------------------------------------------
__global__ __launch_bounds__(256) void cascade_attn_f16(
    const __half* __restrict__ qT,     // [2, PIX, C] fp16
    const __half* __restrict__ kT,
    const __half* __restrict__ vT,
    const int* __restrict__ topk,      // [2,4096,8,2] int32
    const float* __restrict__ relp,    // [2,8,128,128,32] fp32
    float* __restrict__ out_msg,       // [2,16384,256]
    float* __restrict__ out_idx)       // [2,16384,32] (float values)
{
  __shared__ __half kvh[K4 * KSTH];   // gathered K, then V (16,640 B)
  __shared__ __half qph[4 * C];       // q fp16 [t][c]; after QK: probs [h][m][t]

  const int tid = threadIdx.x;
  const int bid = blockIdx.x;
  const int b = bid >> 12;
  const int l = bid & (LBLK - 1);
  const int by = l >> 6, bx = l & 63;
  const int r0 = by * 2, c0 = bx * 2;

  const int* tp = topk + ((size_t)b * LBLK + l) * 16;

  const int h = tid >> 5;   // head
  const int m = tid & 31;   // candidate (QK) / head-dim lane j (PV)

  // ---- stage q: 4 pixels x 256 contiguous halves; 1 uint2 (4 halves)/thread ----
  {
    const int t = tid >> 6, ln = tid & 63;
    const int pix = r0 * W0 + c0 + (t >> 1) * W0 + (t & 1);
    uint2 f = *(const uint2*)&qT[((size_t)b * PIX + pix) * C + ln * 4];
    *(uint2*)&qph[t * C + ln * 4] = f;
  }

  // ---- candidate pixel for this thread's cooperative gather slice ----
  const int p = tid >> 3;        // candidate 0..31
  const int ln8 = tid & 7;
  const int jj = p >> 2, o = p & 3;
  const int gpix = (tp[jj * 2] * 2 + (o >> 1)) * W0 + tp[jj * 2 + 1] * 2 + (o & 1);

  // ---- stage gathered K: 4 x uint4 (8 halves each) per thread ----
  {
    const __half* src = &kT[((size_t)b * PIX + gpix) * C + ln8 * 8];
#pragma unroll
    for (int i = 0; i < 4; ++i) {
      uint4 f = *(const uint4*)(src + i * 64);      // 16B aligned
      __half* dst = &kvh[p * KSTH + ln8 * 8 + i * 64];
      *(uint2*)dst = make_uint2(f.x, f.y);          // 8B aligned (row = 520 B)
      *(uint2*)(dst + 4) = make_uint2(f.z, f.w);
    }
  }

  // ---- prefetch gathered V into registers (latency hides behind QK) ----
  uint4 vreg[4];
  {
    const __half* src = &vT[((size_t)b * PIX + gpix) * C + ln8 * 8];
#pragma unroll
    for (int i = 0; i < 4; ++i) vreg[i] = *(const uint4*)(src + i * 64);
  }

  // ---- prefetch rel_pos for this (h,m): 4 floats, coalesced over m ----
  const size_t rb = ((((size_t)b * NH + h) * H0 + r0) * W0 + c0) * K4 + m;
  float rl0 = relp[rb];
  float rl1 = relp[rb + K4];
  float rl2 = relp[rb + (size_t)W0 * K4];
  float rl3 = relp[rb + (size_t)W0 * K4 + K4];

  // ---- up_idx output: 4 pixels x 32 m per block ----
  if (tid < 128) {
    const int mm = tid & 31, t = tid >> 5;
    const int j2 = mm >> 2, o2 = mm & 3;
    const int pix = (tp[j2 * 2] * 2 + (o2 >> 1)) * W0 + tp[j2 * 2 + 1] * 2 + (o2 & 1);
    const int prow = r0 + (t >> 1), pcol = c0 + (t & 1);
    out_idx[((size_t)b * PIX + prow * W0 + pcol) * K4 + mm] = (float)pix;
  }
  __syncthreads();   // (1) q + K staged

  // ---- load K fragment from LDS: K[m][h*32..+31] as 16 half2 ----
  uint2 kw[8];
  {
    const __half* kbase = &kvh[m * KSTH + h * D];   // 8B aligned
#pragma unroll
    for (int i = 0; i < 8; ++i) kw[i] = *(const uint2*)(kbase + i * 4);
  }
  const half2_t* kh = (const half2_t*)kw;           // 16 half2

  // ---- QK via fdot2: s[t] = q[t,h,:] . K[m,h,:] ----
  float acc[4] = {0.f, 0.f, 0.f, 0.f};
#pragma unroll
  for (int t = 0; t < 4; ++t) {
    uint4 qw[2];
    const uint4* qf = (const uint4*)&qph[t * C + h * D];  // 16B aligned, broadcast
    qw[0] = qf[0];
    qw[1] = qf[1];
    const half2_t* qh2 = (const half2_t*)qw;        // wait: 2 uint4 = 8 half2
    // need 32 halves = 4 uint4; load remaining two
    uint4 qw2[2];
    qw2[0] = qf[2];
    qw2[1] = qf[3];
    const half2_t* qh2b = (const half2_t*)qw2;
#pragma unroll
    for (int i = 0; i < 8; ++i) acc[t] = fdot2_acc(qh2[i], kh[i], acc[t]);
#pragma unroll
    for (int i = 0; i < 8; ++i) acc[t] = fdot2_acc(qh2b[i], kh[8 + i], acc[t]);
  }

  const float scale = 0.17677669529663687f;  // 1/sqrt(32)
  float sv[4];
  sv[0] = acc[0] * scale + rl0;
  sv[1] = acc[1] * scale + rl1;
  sv[2] = acc[2] * scale + rl2;
  sv[3] = acc[3] * scale + rl3;

  // ---- softmax over m (32-lane xor shuffles stay inside the m group) ----
  float pr4[4];
#pragma unroll
  for (int t = 0; t < 4; ++t) {
    float x = sv[t];
    float mx = x;
#pragma unroll
    for (int off = 16; off > 0; off >>= 1) mx = fmaxf(mx, __shfl_xor(mx, off));
    float pbit = __expf(x - mx);
    float sm = pbit;
#pragma unroll
    for (int off = 16; off > 0; off >>= 1) sm += __shfl_xor(sm, off);
    pr4[t] = pbit / sm;
  }
  __syncthreads();   // (2) all QK reads of qph & kvh complete

  // ---- write probs fp16 into qph (q dead) and V into kvh (K dead) ----
  {
    __half2 p01 = __floats2half2_rn(pr4[0], pr4[1]);
    __half2 p23 = __floats2half2_rn(pr4[2], pr4[3]);
    uint2 u;
    u.x = *(unsigned*)&p01;
    u.y = *(unsigned*)&p23;
    *(uint2*)&qph[tid * 4] = u;   // [h][m][t] layout, 8B aligned
  }
#pragma unroll
  for (int i = 0; i < 4; ++i) {
    __half* dst = &kvh[p * KSTH + ln8 * 8 + i * 64];
    *(uint2*)dst = make_uint2(vreg[i].x, vreg[i].y);
    *(uint2*)(dst + 4) = make_uint2(vreg[i].z, vreg[i].w);
  }
  __syncthreads();   // (3) probs + V visible

  // ---- PV: out[t,h,j] = sum_m A[t,h,m] * V[m,h,j] ----
  float o0 = 0.f, o1 = 0.f, o2 = 0.f, o3 = 0.f;
#pragma unroll
  for (int mm = 0; mm < 32; ++mm) {
    uint2 au = *(const uint2*)&qph[(h * K4 + mm) * 4];  // broadcast per h-group
    __half2 a01 = *(__half2*)&au.x;
    __half2 a23 = *(__half2*)&au.y;
    float2 f01 = __half22float2(a01);
    float2 f23 = __half22float2(a23);
    float vv = __half2float(kvh[mm * KSTH + h * D + m]); // <=2-way banks
    o0 += f01.x * vv;
    o1 += f01.y * vv;
    o2 += f23.x * vv;
    o3 += f23.y * vv;
  }
  const size_t ob = ((size_t)b * PIX + (size_t)r0 * W0 + c0) * C + h * D + m;
  out_msg[ob] = o0;
  out_msg[ob + C] = o1;
  out_msg[ob + (size_t)W0 * C] = o2;
  out_msg[ob + (size_t)W0 * C + C] = o3;
}

// ---------------------------------------------------------------------------
// Fallback (Round-1 kernel, known correct): used only if ws too small.
// ---------------------------------------------------------------------------
__global__ __launch_bounds__(256) void cascade_attn_fallback(
    const float* __restrict__ query, const float* __restrict__ key,
    const float* __restrict__ value, const int* __restrict__ topk,
    const float* __restrict__ relp, float* __restrict__ out_msg,
    float* __restrict__ out_idx)
{
  __shared__ float kv[K4 * KST];
  __shared__ float qs[4 * C];
  __shared__ float as_[NH * K4 * 4];

  const int tid = threadIdx.x;
  const int bid = blockIdx.x;
  const int b = bid >> 12;
  const int l = bid & (LBLK - 1);
  const int by = l >> 6, bx = l & 63;
  const int r0 = by * 2, c0 = bx * 2;

  const size_t plane = (size_t)PIX;
  const float* qb = query + (size_t)b * C * plane;
  const float* kb = key + (size_t)b * C * plane;
  const float* vb = value + (size_t)b * C * plane;
  const int* tp = topk + ((size_t)b * LBLK + l) * 16;

  {
    const float* qp = qb + (size_t)tid * plane + r0 * W0 + c0;
    float2 a = *(const float2*)qp;
    float2 bb = *(const float2*)(qp + W0);
    qs[0 * C + tid] = a.x; qs[1 * C + tid] = a.y;
    qs[2 * C + tid] = bb.x; qs[3 * C + tid] = bb.y;
  }
#pragma unroll
  for (int it = 0; it < 16; ++it) {
    const int jj = it >> 1, x = it & 1;
    const int pr = tp[jj * 2] * 2 + x;
    const int pc = tp[jj * 2 + 1] * 2;
    float2 f = *(const float2*)(kb + (size_t)tid * plane + pr * W0 + pc);
    const int m0 = jj * 4 + x * 2;
    kv[m0 * KST + tid] = f.x;
    kv[(m0 + 1) * KST + tid] = f.y;
  }
  if (tid < 128) {
    const int m = tid & 31, t = tid >> 5;
    const int jj = m >> 2, o = m & 3;
    const int pix = (tp[jj * 2] * 2 + (o >> 1)) * W0 + tp[jj * 2 + 1] * 2 + (o & 1);
    const int prow = r0 + (t >> 1), pcol = c0 + (t & 1);
    out_idx[((size_t)b * plane + prow * W0 + pcol) * K4 + m] = (float)pix;
  }
  __syncthreads();

  const int h = tid >> 5;
  const int m = tid & 31;
  float a0 = 0.f, a1 = 0.f, a2 = 0.f, a3 = 0.f;
#pragma unroll
  for (int dq = 0; dq < 8; ++dq) {
    const int off = h * D + dq * 4;
    float4 q0 = *(const float4*)&qs[0 * C + off];
    float4 q1 = *(const float4*)&qs[1 * C + off];
    float4 q2 = *(const float4*)&qs[2 * C + off];
    float4 q3 = *(const float4*)&qs[3 * C + off];
    float2 ka = *(const float2*)&kv[m * KST + off];
    float2 kc = *(const float2*)&kv[m * KST + off + 2];
    a0 += q0.x * ka.x + q0.y * ka.y + q0.z * kc.x + q0.w * kc.y;
    a1 += q1.x * ka.x + q1.y * ka.y + q1.z * kc.x + q1.w * kc.y;
    a2 += q2.x * ka.x + q2.y * ka.y + q2.z * kc.x + q2.w * kc.y;
    a3 += q3.x * ka.x + q3.y * ka.y + q3.z * kc.x + q3.w * kc.y;
  }
  const float scale = 0.17677669529663687f;
  const size_t rb = ((((size_t)b * NH + h) * H0 + r0) * W0 + c0) * K4 + m;
  float sv[4];
  sv[0] = a0 * scale + relp[rb];
  sv[1] = a1 * scale + relp[rb + K4];
  sv[2] = a2 * scale + relp[rb + (size_t)W0 * K4];
  sv[3] = a3 * scale + relp[rb + (size_t)W0 * K4 + K4];
  float pr4[4];
#pragma unroll
  for (int t = 0; t < 4; ++t) {
    float x = sv[t];
    float mx = x;
#pragma unroll
    for (int off = 16; off > 0; off >>= 1) mx = fmaxf(mx, __shfl_xor(mx, off));
    float pbit = __expf(x - mx);
    float sm = pbit;
#pragma unroll
    for (int off = 16; off > 0; off >>= 1) sm += __shfl_xor(sm, off);
    pr4[t] = pbit / sm;
  }
  *(float4*)&as_[tid * 4] = make_float4(pr4[0], pr4[1], pr4[2], pr4[3]);
  __syncthreads();
#pragma unroll
  for (int it = 0; it < 16; ++it) {
    const int jj = it >> 1, x = it & 1;
    const int pr = tp[jj * 2] * 2 + x;
    const int pc = tp[jj * 2 + 1] * 2;
    float2 f = *(const float2*)(vb + (size_t)tid * plane + pr * W0 + pc);
    const int m0 = jj * 4 + x * 2;
    kv[m0 * KST + tid] = f.x;
    kv[(m0 + 1) * KST + tid] = f.y;
  }
  __syncthreads();
  float o0 = 0.f, o1 = 0.f, o2 = 0.f, o3 = 0.f;
#pragma unroll
  for (int mm = 0; mm < 32; ++mm) {
    float4 a4 = *(const float4*)&as_[(h * K4 + mm) * 4];
    float vv = kv[mm * KST + h * D + m];
    o0 += a4.x * vv; o1 += a4.y * vv; o2 += a4.z * vv; o3 += a4.w * vv;
  }
  const size_t ob = ((size_t)b * plane + (size_t)r0 * W0 + c0) * C + h * D + m;
  out_msg[ob] = o0;
  out_msg[ob + C] = o1;
  out_msg[ob + (size_t)W0 * C] = o2;
  out_msg[ob + (size_t)W0 * C + C] = o3;
}

extern "C" void kernel_launch(void* const* d_in, const int* in_sizes, int n_in,
                              void* d_out, int out_size, void* d_ws, size_t ws_size,
                              hipStream_t stream) {
  const float* q = (const float*)d_in[0];
  const float* k = (const float*)d_in[1];
  const float* v = (const float*)d_in[2];
  const int* tp = (const int*)d_in[3];
  const float* rp = (const float*)d_in[4];

  float* out_msg = (float*)d_out;
  float* out_idx = out_msg + (size_t)2 * PIX * C;

  const size_t n_elem = (size_t)2 * PIX * C;
  const size_t needed = 3 * n_elem * sizeof(__half);  // 50.3 MB
  if (ws_size >= needed) {
    __half* qT = (__half*)d_ws;
    __half* kT = qT + n_elem;
    __half* vT = kT + n_elem;
    dim3 tg(PIX / 64, C / 64, 6);
    hipLaunchKernelGGL(transpose_qkv_kernel, tg, dim3(256), 0, stream,
                       q, k, v, qT, kT, vT);
    hipLaunchKernelGGL(cascade_attn_f16, dim3(2 * LBLK), dim3(256), 0, stream,
                       qT, kT, vT, tp, rp, out_msg, out_idx);
  } else {
    hipLaunchKernelGGL(cascade_attn_fallback, dim3(2 * LBLK), dim3(256), 0, stream,
                       q, k, v, tp, rp, out_msg, out_idx);
  }
}